// Round 2
// baseline (504.300 us; speedup 1.0000x reference)
//
#include <hip/hip_runtime.h>

// ManifoldNetSPD SPD identity-pad:
//   x: [8,16,256,256,3,3] f32  ->  out: [8,16,258,258,3,3] f32
//   border cells (pad ring) = eye(3), interior = copy.
//
// Round 2: one block per full output row. Row bases are 8B-aligned
// (ROW_OUT*4 = 9288 ≡ 0 mod 8), so the whole 2322-float row is written as
// aligned float2 stores — border cells (j=0, j=257, full rows i=0/257)
// emitted inline in the same contiguous stream. The 9-float src shift is
// absorbed on the READ side (dword loads, alignment-tolerant). No scattered
// border writes, no second code path straggling the dispatch.

constexpr int HP = 258, WP = 258;
constexpr int ROW_IN  = 256 * 9;        // 2304 floats
constexpr int IMG_IN  = 256 * ROW_IN;   // per-image input floats
constexpr int ROW_OUT = WP * 9;         // 2322 floats
constexpr int IMG_OUT = HP * ROW_OUT;   // 599076 floats
constexpr int F2_PER_ROW = ROW_OUT / 2; // 1161 float2 per row
constexpr int IMGS = 8 * 16;            // 128
constexpr int NBLOCKS = IMGS * HP;      // 33024

typedef float v2f __attribute__((ext_vector_type(2)));

__device__ __forceinline__ float eye_val(int e) {
    return (e == 0 || e == 4 || e == 8) ? 1.0f : 0.0f;
}

__global__ __launch_bounds__(256) void spd_pad_rows(const float* __restrict__ x,
                                                    float* __restrict__ out) {
    const int blk = blockIdx.x;
    const int img = blk / HP;            // 0..127
    const int i   = blk - img * HP;      // output row 0..257
    float* __restrict__ drow = out + img * IMG_OUT + i * ROW_OUT;  // 8B-aligned
    v2f* __restrict__ drow2 = reinterpret_cast<v2f*>(drow);

    if (i == 0 || i == HP - 1) {
        // Full eye row: value at float index c is eye[c % 9].
        for (int idx = threadIdx.x; idx < F2_PER_ROW; idx += 256) {
            const int c  = idx * 2;
            const int e0 = c % 9;
            const int e1 = (e0 == 8) ? 0 : e0 + 1;
            v2f v;
            v.x = eye_val(e0);
            v.y = eye_val(e1);
            __builtin_nontemporal_store(v, drow2 + idx);
        }
    } else {
        // Interior row: floats [9, 2312] copy src row (i-1); ends are eye.
        const float* __restrict__ srow = x + img * IMG_IN + (i - 1) * ROW_IN;
        for (int idx = threadIdx.x; idx < F2_PER_ROW; idx += 256) {
            const int c = idx * 2;       // first float index of this pair
            v2f v;
            if (c >= 10 && c <= 2310) {
                // both floats interior: src floats c-9 (odd), c-8
                v.x = __builtin_nontemporal_load(srow + c - 9);
                v.y = __builtin_nontemporal_load(srow + c - 8);
            } else {
                const int c1 = c + 1;
                v.x = (c  < 9) ? eye_val(c)
                     : (c  >= 2313 ? eye_val(c  - 2313)
                                   : __builtin_nontemporal_load(srow + c  - 9));
                v.y = (c1 < 9) ? eye_val(c1)
                     : (c1 >= 2313 ? eye_val(c1 - 2313)
                                   : __builtin_nontemporal_load(srow + c1 - 9));
            }
            __builtin_nontemporal_store(v, drow2 + idx);
        }
    }
}

extern "C" void kernel_launch(void* const* d_in, const int* in_sizes, int n_in,
                              void* d_out, int out_size, void* d_ws, size_t ws_size,
                              hipStream_t stream) {
    const float* x   = (const float*)d_in[0];
    float*       out = (float*)d_out;
    // d_in[1] is padding_dim (==1), baked into the constants above.
    spd_pad_rows<<<dim3(NBLOCKS), dim3(256), 0, stream>>>(x, out);
}